// Round 12
// baseline (48.601 us; speedup 1.0000x reference)
//
#include <hip/hip_runtime.h>

// LowRankSig_HigherOrder: B=32, T=2048, F=64 (time + 63), K=10 tensors, U=64 units.
// Round 12 = round 11 (MFMA bf16 2-term split, frag-major coalesced B, affine
// scan maps) restructured for 2-waves/SIMD residency + shorter serial tail:
//  - ONE rolling double-buffer (bh0/bl0, bh1/bl1 = 64 VGPR) for B-frags across
//    ALL 10 nt steps (r11 held 96 VGPR of phase-A frags through staging ->
//    unified-file footprint >256 -> 1 wave/SIMD, Occupancy 8.9%).
//  - phase scans placed INSIDE the nt pipeline: scanA runs while nt3/nt4 fly,
//    scanB covers nt6/nt7. acc arrays scoped per phase -> AGPR peak 64.
//  - scan C: 4 independent run-chains scanned first (4-way ILP), shfls
//    batched, then a compose TREE (pair,pair,final) instead of serial fold.
//  - partial+final combine merged into one kernel (LDS handoff).
// C/D layout (HW-verified m74/m101): col=lane&31, row=(reg&3)+8*(reg>>2)+4*hi8.
// Maps/compose family validated rounds 1-11.

#define TT 2048
#define NFX 63
#define KT 10
#define NU 64
#define NQ 17
#define NCC 32       // 64-row chunks per batch (ws map layout)
#define NSEG 4       // combine segments (8 maps each)

#define MAPS_BYTES (32u * NCC * NQ * NU * 4u)          // 4,456,448 B
#define PLANE      40960u                              // elems per bf16 plane

typedef __attribute__((ext_vector_type(16))) float f32x16v;
typedef __attribute__((ext_vector_type(8)))  short bf16x8v;

enum {Qo=0, Qa1, Qa3, QaA, Qa6, QaP, QaQ, Qd1, Qd3, QdA, Qd6, QdP, QdQ,
      QtA3, QtP6, QtQP, QtQ6};

__device__ __forceinline__ unsigned short bf16_rne(float x) {
  unsigned int u = __float_as_uint(x);
  unsigned int r = (u + 0x7FFFu + ((u >> 16) & 1u)) >> 16;
  return (unsigned short)r;
}
__device__ __forceinline__ float bf16f(unsigned short h) {
  return __uint_as_float(((unsigned int)h) << 16);
}

// compose earlier map q1 with later map q2 -> r (family closed; r2/r7-validated)
__device__ __forceinline__ void compose_maps(const float* q1, const float* q2,
                                             float* r)
{
  r[Qo]  = q1[Qo] + q2[Qo]
         + q2[Qa1]*q1[Qd1] + q2[Qa3]*q1[Qd3] + q2[QaA]*q1[QdA]
         + q2[Qa6]*q1[Qd6] + q2[QaP]*q1[QdP] + q2[QaQ]*q1[QdQ];
  r[Qa1] = q1[Qa1] + q2[Qa1];
  r[Qa3] = q1[Qa3] + q2[Qa3] + q1[QtA3]*q2[QaA];
  r[QaA] = q1[QaA] + q2[QaA];
  r[Qa6] = q1[Qa6] + q2[Qa6] + q1[QtP6]*q2[QaP] + q1[QtQ6]*q2[QaQ];
  r[QaP] = q1[QaP] + q2[QaP] + q1[QtQP]*q2[QaQ];
  r[QaQ] = q1[QaQ] + q2[QaQ];
  r[Qd1] = q1[Qd1] + q2[Qd1];
  r[Qd3] = q1[Qd3] + q2[Qd3];
  r[QdA] = q1[QdA] + q2[QdA] + q2[QtA3]*q1[Qd3];
  r[Qd6] = q1[Qd6] + q2[Qd6];
  r[QdP] = q1[QdP] + q2[QdP] + q2[QtP6]*q1[Qd6];
  r[QdQ] = q1[QdQ] + q2[QdQ] + q2[QtQP]*q1[QdP] + q2[QtQ6]*q1[Qd6];
  r[QtA3] = q1[QtA3] + q2[QtA3];
  r[QtP6] = q1[QtP6] + q2[QtP6];
  r[QtQP] = q1[QtQP] + q2[QtQP];
  r[QtQ6] = q1[QtQ6] + q2[QtQ6] + q2[QtQP]*q1[QtP6];
}

// ---- prep: split Kw into bf16 hi/lo planes, FRAG-MAJOR layout:
//      idx = (((nt*2 + ub)*4 + ks)*64 + lane)*8 + j
//      lane=(hi8*32+col): f = ks*16 + hi8*8 + j, u = ub*32 + col, k = nt.
__global__ __launch_bounds__(256)
void lrsig_prep_kernel(const float* __restrict__ Kw,
                       unsigned short* __restrict__ kwb)
{
  int e = blockIdx.x * 256 + threadIdx.x;    // 0..40959 (destination index)
  int j  = e & 7;
  int l  = (e >> 3) & 63;
  int ks = (e >> 9) & 3;
  int ub = (e >> 11) & 1;
  int nt = e >> 12;
  int f = ks * 16 + (l >> 5) * 8 + j;
  int u = ub * 32 + (l & 31);
  float x = Kw[(f * KT + nt) * NU + u];
  unsigned short hi = bf16_rne(x);
  unsigned short lo = bf16_rne(x - bf16f(hi));
  kwb[e] = hi;
  kwb[PLANE + e] = lo;
}

#define LOADB(BUF, S) do {                                                   \
  _Pragma("unroll")                                                          \
  for (int ks = 0; ks < 4; ++ks) {                                           \
    const unsigned short* bp = kwb + ((((S) * 2 + ub) * 4 + ks) * 512) + l*8;\
    bh##BUF[ks] = *(const bf16x8v*)(bp);                                     \
    bl##BUF[ks] = *(const bf16x8v*)(bp + PLANE);                             \
  } } while (0)

#define MFMA12(ACC, BUF) do {                                                \
  _Pragma("unroll")                                                          \
  for (int ks = 0; ks < 4; ++ks) {                                           \
    ACC = __builtin_amdgcn_mfma_f32_32x32x16_bf16(ah[ks], bh##BUF[ks], ACC, 0,0,0); \
    ACC = __builtin_amdgcn_mfma_f32_32x32x16_bf16(al[ks], bh##BUF[ks], ACC, 0,0,0); \
    ACC = __builtin_amdgcn_mfma_f32_32x32x16_bf16(ah[ks], bl##BUF[ks], ACC, 0,0,0); \
  } } while (0)

#define ZERO(ACC) do { _Pragma("unroll")                                     \
  for (int zi = 0; zi < 16; ++zi) ACC[zi] = 0.f; } while (0)

__global__ __launch_bounds__(256)
void lrsig_chunk_kernel(const float* __restrict__ X,
                        const unsigned short* __restrict__ kwb,
                        float* __restrict__ wmaps)
{
  // 32768 B total:
  //   bytes [0,8192)      : dXa bf16 hi plane, swizzled [64 rows][128 B]
  //   bytes [8192,16384)  : lo plane
  //   floats [4096,8191]  : raw fp32 X tile during staging; after MFMA reused
  //                         as map slots [2 rt][NQ][NU]
  __shared__ __align__(16) float smemf[8192];
  char* smem = (char*)smemf;
  float* rawf = smemf + 4096;

  const int b   = blockIdx.y;
  const int c   = blockIdx.x;        // 0..31, 64 rows per WG
  const int tid = threadIdx.x;
  const int l   = tid & 63;
  const int w   = tid >> 6;          // wave 0..3
  const int rt  = w >> 1;            // row-tile (rows rt*32 .. +31)
  const int ub  = w & 1;             // u-block  (u = ub*32 + col)
  const int col = l & 31;
  const int hi8 = l >> 5;
  const int t0  = c * 64;

  // ---- 1. batch-issue the 16 staging loads (rows t0-1 .. t0+63, 65x63) ----
  float sv[16];
  {
    const float* Xb = X + (size_t)b * TT * NFX;
    const int base = (t0 - 1) * NFX;
#pragma unroll
    for (int ii = 0; ii < 16; ++ii) {
      int i = tid + ii * 256;
      int off = base + i + ((c == 0 && i < NFX) ? NFX : 0); // c==0: dup row 0
      sv[ii] = (i < 65 * NFX) ? Xb[off] : 0.f;
    }
  }

  // ---- 2. issue nt0's B-frags only (32 VGPR); they land under staging ----
  bf16x8v bh0[4], bl0[4], bh1[4], bl1[4];
  LOADB(0, 0);

  // ---- 3. store staged tile to LDS ----
#pragma unroll
  for (int ii = 0; ii < 16; ++ii) {
    int i = tid + ii * 256;
    if (i < 65 * NFX) rawf[i] = sv[ii];
  }
  __syncthreads();

  // ---- 4. diff + bf16 hi/lo split into swizzled planes ----
  {
    float v0[16], v1[16];
#pragma unroll
    for (int ii = 0; ii < 16; ++ii) {
      int e = tid + ii * 256;
      if (e < 64 * NFX) { v0[ii] = rawf[e]; v1[ii] = rawf[e + NFX]; }
    }
#pragma unroll
    for (int ii = 0; ii < 16; ++ii) {
      int e = tid + ii * 256;
      if (e < 64 * NFX) {
        int r2 = e / NFX;
        int c2 = e - r2 * NFX;             // feature-1 (features 1..63)
        float d = v1[ii] - v0[ii];         // row-0 dup makes t=0 diff zero
        unsigned short h  = bf16_rne(d);
        unsigned short lo = bf16_rne(d - bf16f(h));
        int byte = r2 * 128 + ((2 * (c2 + 1)) ^ ((r2 & 7) << 4));
        *(unsigned short*)(smem + byte)        = h;
        *(unsigned short*)(smem + 8192 + byte) = lo;
      }
    }
  }
  if (tid < 64) {                      // time feature f=0
    int r2 = tid;
    float d = (t0 + r2 == 0) ? 0.f : (2.0f / 2047.0f);
    unsigned short h  = bf16_rne(d);
    unsigned short lo = bf16_rne(d - bf16f(h));
    int byte = r2 * 128 + ((0) ^ ((r2 & 7) << 4));
    *(unsigned short*)(smem + byte)        = h;
    *(unsigned short*)(smem + 8192 + byte) = lo;
  }
  __syncthreads();

  const int row = rt * 32 + col;
  const int colbase = ub * 32 + col;

  // ---- A-frags once for all phases (same row) ----
  bf16x8v ah[4], al[4];
#pragma unroll
  for (int ks = 0; ks < 4; ++ks) {
    const int f0 = ks * 16 + hi8 * 8;
    const int abyte = row * 128 + ((2 * f0) ^ ((row & 7) << 4));
    ah[ks] = *(const bf16x8v*)(smem + abyte);
    al[ks] = *(const bf16x8v*)(smem + 8192 + abyte);
  }

  // ---- rolling nt pipeline: nt s lives in buf s&1; scans fill load gaps ----
  float Ao[4], Aa1[4], Ad1[4];
  float Ba3[4], BaA[4], Bd3[4], BdA[4], BtA3[4];

  // phase A: nt 0,1,2
  {
    f32x16v accA[3];
    ZERO(accA[0]); ZERO(accA[1]); ZERO(accA[2]);
    LOADB(1, 1);  MFMA12(accA[0], 0);
    LOADB(0, 2);  MFMA12(accA[1], 1);
    LOADB(1, 3);  MFMA12(accA[2], 0);
    // scan chain A per 4-row run (covers nt3/nt4 load latency)
#pragma unroll
    for (int j = 0; j < 4; ++j) {
      float o = 0.f, a1 = 0.f, lc1 = 0.f;
#pragma unroll
      for (int i = 0; i < 4; ++i) {
        const int r = 4 * j + i;
        float m0 = accA[0][r], m1 = accA[1][r], m2 = accA[2][r];
        o   += m0 + m2 * (lc1 + 0.5f * m1);
        a1  += m2;
        lc1 += m1;
      }
      Ao[j] = o; Aa1[j] = a1; Ad1[j] = lc1;
    }
  }

  // phase B: nt 3,4,5
  {
    f32x16v accB[3];
    ZERO(accB[0]); ZERO(accB[1]); ZERO(accB[2]);
    LOADB(0, 4);  MFMA12(accB[0], 1);
    LOADB(1, 5);  MFMA12(accB[1], 0);
    LOADB(0, 6);  MFMA12(accB[2], 1);
    // scan chain B per run (covers nt6/nt7 load latency)
#pragma unroll
    for (int j = 0; j < 4; ++j) {
      float o = 0.f, a3 = 0.f, aA = 0.f, lc3 = 0.f, lcA = 0.f, g4 = 0.f;
#pragma unroll
      for (int i = 0; i < 4; ++i) {
        const int r = 4 * j + i;
        float m3 = accB[0][r], m4 = accB[1][r], m5 = accB[2][r];
        float s0 = m4 * lc3;
        float s1 = 0.5f * m4 * m3;
        o   += m5 * (lcA + 0.5f * s0 + (1.f/3.f) * s1);
        a3  += m5 * (g4 + 0.5f * m4);
        aA  += m5;
        lcA += s0 + s1;
        g4  += m4;
        lc3 += m3;
      }
      Ao[j] += o;
      Ba3[j] = a3; BaA[j] = aA; Bd3[j] = lc3; BdA[j] = lcA; BtA3[j] = g4;
    }
  }

  // phase C: nt 6,7,8,9 + scan (4-way ILP) + compose tree
  float tot[NQ];
  {
    f32x16v accC[4];
    ZERO(accC[0]); ZERO(accC[1]); ZERO(accC[2]); ZERO(accC[3]);
    LOADB(1, 7);  MFMA12(accC[0], 0);
    LOADB(0, 8);  MFMA12(accC[1], 1);
    LOADB(1, 9);  MFMA12(accC[2], 0);
                  MFMA12(accC[3], 1);

    // 4 independent run-scans (ILP), full 17-param maps
    float mjv[4][NQ];
#pragma unroll
    for (int j = 0; j < 4; ++j) {
      float o = 0.f, a6 = 0.f, aP = 0.f, aQ = 0.f;
      float lc6 = 0.f, lcP = 0.f, lcQ = 0.f, g7 = 0.f, g8 = 0.f, hh = 0.f;
#pragma unroll
      for (int i = 0; i < 4; ++i) {
        const int r = 4 * j + i;
        float m6 = accC[0][r], m7 = accC[1][r], m8 = accC[2][r], m9 = accC[3][r];
        float p0 = m7 * lc6;
        float p1 = 0.5f * m7 * m6;
        float q0 = m8 * lcP;
        float q1 = 0.5f * m8 * p0;
        float q2 = (1.f/3.f) * m8 * p1;
        o   += m9 * (lcQ + 0.5f * q0 + (1.f/3.f) * q1 + 0.25f * q2);
        a6  += m9 * (hh + m8 * (0.5f * g7 + (1.f/6.f) * m7));
        aP  += m9 * (g8 + 0.5f * m8);
        aQ  += m9;
        hh  += m8 * (g7 + 0.5f * m7);   // exclusive g7, before update
        lcP += p0 + p1;
        lcQ += q0 + q1 + q2;
        g7 += m7; g8 += m8; lc6 += m6;
      }
      mjv[j][Qo] = Ao[j] + o;
      mjv[j][Qa1] = Aa1[j]; mjv[j][Qa3] = Ba3[j]; mjv[j][QaA] = BaA[j];
      mjv[j][Qa6] = a6;     mjv[j][QaP] = aP;     mjv[j][QaQ] = aQ;
      mjv[j][Qd1] = Ad1[j]; mjv[j][Qd3] = Bd3[j]; mjv[j][QdA] = BdA[j];
      mjv[j][Qd6] = lc6;    mjv[j][QdP] = lcP;    mjv[j][QdQ] = lcQ;
      mjv[j][QtA3] = BtA3[j]; mjv[j][QtP6] = g7;
      mjv[j][QtQP] = g8;      mjv[j][QtQ6] = hh;
    }

    // batched shfl (g even <-> g odd) + pair compose -> 8-row maps
    float m8v[4][NQ];
#pragma unroll
    for (int j = 0; j < 4; ++j) {
      float q1v[NQ], q2v[NQ];
#pragma unroll
      for (int q = 0; q < NQ; ++q) {
        float oth = __shfl_xor(mjv[j][q], 32);
        q1v[q] = hi8 ? oth : mjv[j][q];   // even g = earlier rows
        q2v[q] = hi8 ? mjv[j][q] : oth;
      }
      compose_maps(q1v, q2v, m8v[j]);
    }
    // compose tree: (0,1) (2,3) -> final
    float m16a[NQ], m16b[NQ];
    compose_maps(m8v[0], m8v[1], m16a);
    compose_maps(m8v[2], m8v[3], m16b);
    compose_maps(m16a, m16b, tot);
  }

  // ---- write the two 32-row maps (one per rt) into LDS (raw area is dead) --
  if (hi8 == 0) {
    float* p = &rawf[(rt * NQ) * NU + colbase];
#pragma unroll
    for (int q = 0; q < NQ; ++q) p[q * NU] = tot[q];
  }
  __syncthreads();

  // ---- final compose rt0 o rt1 -> 64-row WG map -> ws ----
  if (tid < NU) {
    const int uu = tid;
    float q1v[NQ], q2v[NQ], rv[NQ];
#pragma unroll
    for (int q = 0; q < NQ; ++q) {
      q1v[q] = rawf[(0 * NQ + q) * NU + uu];
      q2v[q] = rawf[(1 * NQ + q) * NU + uu];
    }
    compose_maps(q1v, q2v, rv);
    float* p = &wmaps[(((size_t)b * NCC + c) * NQ) * NU + uu];
#pragma unroll
    for (int q = 0; q < NQ; ++q) p[q * NU] = rv[q];
  }
}

// ---- combine: partial 8-map folds (4 segs x 64 u) + LDS handoff + final ----
__global__ __launch_bounds__(256)
void lrsig_combine_kernel(const float* __restrict__ wmaps,
                          float* __restrict__ out)
{
  __shared__ float sm[NSEG * NQ * NU];   // 17408 B
  const int b   = blockIdx.x;            // 32 blocks
  const int seg = threadIdx.x >> 6;      // 0..3
  const int u   = threadIdx.x & 63;

  float tot[NQ];
  {
    const float* p0 = &wmaps[(((size_t)b * NCC + seg * 8) * NQ) * NU + u];
#pragma unroll
    for (int q = 0; q < NQ; ++q) tot[q] = p0[q * NU];
  }
  for (int i = 1; i < 8; ++i) {
    const float* p = &wmaps[(((size_t)b * NCC + seg * 8 + i) * NQ) * NU + u];
    float m[NQ], r[NQ];
#pragma unroll
    for (int q = 0; q < NQ; ++q) m[q] = p[q * NU];
    compose_maps(tot, m, r);
#pragma unroll
    for (int q = 0; q < NQ; ++q) tot[q] = r[q];
  }
#pragma unroll
  for (int q = 0; q < NQ; ++q) sm[(seg * NQ + q) * NU + u] = tot[q];
  __syncthreads();

  if (threadIdx.x < NU) {
    const int uu = threadIdx.x;
    float c1 = 0.f, c3 = 0.f, cA = 0.f, c6 = 0.f, cP = 0.f, cQ = 0.f, o = 0.f;
#pragma unroll
    for (int s = 0; s < NSEG; ++s) {
      float q[NQ];
#pragma unroll
      for (int i = 0; i < NQ; ++i) q[i] = sm[(s * NQ + i) * NU + uu];
      o  += q[0] + q[1]*c1 + q[2]*c3 + q[3]*cA + q[4]*c6 + q[5]*cP + q[6]*cQ;
      cA += q[13]*c3 + q[9];             // uses c3_in
      cQ += q[15]*cP + q[16]*c6 + q[12]; // uses cP_in, c6_in
      cP += q[14]*c6 + q[11];            // uses c6_in
      c1 += q[7]; c3 += q[8]; c6 += q[10];
    }
    out[b * 64 + uu] = o;
  }
}

extern "C" void kernel_launch(void* const* d_in, const int* in_sizes, int n_in,
                              void* d_out, int out_size, void* d_ws, size_t ws_size,
                              hipStream_t stream) {
  const float* X  = (const float*)d_in[0];   // (32, 2048, 63) fp32
  const float* Kw = (const float*)d_in[1];   // (64, 10, 64)   fp32
  float* out = (float*)d_out;                // (32, 64)       fp32
  float* wmaps = (float*)d_ws;                                    // 4.45 MB
  unsigned short* kwb = (unsigned short*)((char*)d_ws + MAPS_BYTES); // 160 KB

  hipLaunchKernelGGL(lrsig_prep_kernel, dim3(160), dim3(256), 0, stream,
                     Kw, kwb);
  hipLaunchKernelGGL(lrsig_chunk_kernel, dim3(NCC, 32), dim3(256), 0, stream,
                     X, kwb, wmaps);
  hipLaunchKernelGGL(lrsig_combine_kernel, dim3(32), dim3(256), 0, stream,
                     wmaps, out);
}

// Round 13
// 48.425 us; speedup vs baseline: 1.0036x; 1.0036x over previous
//
#include <hip/hip_runtime.h>

// LowRankSig_HigherOrder: B=32, T=2048, F=64 (time + 63), K=10 tensors, U=64 units.
// Round 13 = round 12 (MFMA bf16 2-term split, frag-major coalesced B, affine
// scan maps, merged combine) with a real register diet to reach 2 waves/SIMD
// (r11/r12 sat at ~296 regs/wave -> 1 wave/SIMD, Occupancy 9%):
//  - SINGLE B buffer (bh/bl = 32 VGPR, was 64): latency hiding now comes from
//    the co-resident second wave, not in-wave double buffering.
//  - phase-C SERIAL tail: per run j: scan -> mj -> shfl -> compose -> fold
//    into tot immediately. Peak tail liveness ~70 floats (r12 tree kept
//    mjv[4]+m8v[4] = 136 floats live).
//  - peak estimate ~230 regs < 256 -> 2 waves/SIMD.
// C/D layout (HW-verified m74/m101): col=lane&31, row=(reg&3)+8*(reg>>2)+4*hi8.
// Maps/compose family validated rounds 1-12.

#define TT 2048
#define NFX 63
#define KT 10
#define NU 64
#define NQ 17
#define NCC 32       // 64-row chunks per batch (ws map layout)
#define NSEG 4       // combine segments (8 maps each)

#define MAPS_BYTES (32u * NCC * NQ * NU * 4u)          // 4,456,448 B
#define PLANE      40960u                              // elems per bf16 plane

typedef __attribute__((ext_vector_type(16))) float f32x16v;
typedef __attribute__((ext_vector_type(8)))  short bf16x8v;

enum {Qo=0, Qa1, Qa3, QaA, Qa6, QaP, QaQ, Qd1, Qd3, QdA, Qd6, QdP, QdQ,
      QtA3, QtP6, QtQP, QtQ6};

__device__ __forceinline__ unsigned short bf16_rne(float x) {
  unsigned int u = __float_as_uint(x);
  unsigned int r = (u + 0x7FFFu + ((u >> 16) & 1u)) >> 16;
  return (unsigned short)r;
}
__device__ __forceinline__ float bf16f(unsigned short h) {
  return __uint_as_float(((unsigned int)h) << 16);
}

// compose earlier map q1 with later map q2 -> r (family closed; r2/r7-validated)
__device__ __forceinline__ void compose_maps(const float* q1, const float* q2,
                                             float* r)
{
  r[Qo]  = q1[Qo] + q2[Qo]
         + q2[Qa1]*q1[Qd1] + q2[Qa3]*q1[Qd3] + q2[QaA]*q1[QdA]
         + q2[Qa6]*q1[Qd6] + q2[QaP]*q1[QdP] + q2[QaQ]*q1[QdQ];
  r[Qa1] = q1[Qa1] + q2[Qa1];
  r[Qa3] = q1[Qa3] + q2[Qa3] + q1[QtA3]*q2[QaA];
  r[QaA] = q1[QaA] + q2[QaA];
  r[Qa6] = q1[Qa6] + q2[Qa6] + q1[QtP6]*q2[QaP] + q1[QtQ6]*q2[QaQ];
  r[QaP] = q1[QaP] + q2[QaP] + q1[QtQP]*q2[QaQ];
  r[QaQ] = q1[QaQ] + q2[QaQ];
  r[Qd1] = q1[Qd1] + q2[Qd1];
  r[Qd3] = q1[Qd3] + q2[Qd3];
  r[QdA] = q1[QdA] + q2[QdA] + q2[QtA3]*q1[Qd3];
  r[Qd6] = q1[Qd6] + q2[Qd6];
  r[QdP] = q1[QdP] + q2[QdP] + q2[QtP6]*q1[Qd6];
  r[QdQ] = q1[QdQ] + q2[QdQ] + q2[QtQP]*q1[QdP] + q2[QtQ6]*q1[Qd6];
  r[QtA3] = q1[QtA3] + q2[QtA3];
  r[QtP6] = q1[QtP6] + q2[QtP6];
  r[QtQP] = q1[QtQP] + q2[QtQP];
  r[QtQ6] = q1[QtQ6] + q2[QtQ6] + q2[QtQP]*q1[QtP6];
}

// ---- prep: split Kw into bf16 hi/lo planes, FRAG-MAJOR layout:
//      idx = (((nt*2 + ub)*4 + ks)*64 + lane)*8 + j
//      lane=(hi8*32+col): f = ks*16 + hi8*8 + j, u = ub*32 + col, k = nt.
__global__ __launch_bounds__(256)
void lrsig_prep_kernel(const float* __restrict__ Kw,
                       unsigned short* __restrict__ kwb)
{
  int e = blockIdx.x * 256 + threadIdx.x;    // 0..40959 (destination index)
  int j  = e & 7;
  int l  = (e >> 3) & 63;
  int ks = (e >> 9) & 3;
  int ub = (e >> 11) & 1;
  int nt = e >> 12;
  int f = ks * 16 + (l >> 5) * 8 + j;
  int u = ub * 32 + (l & 31);
  float x = Kw[(f * KT + nt) * NU + u];
  unsigned short hi = bf16_rne(x);
  unsigned short lo = bf16_rne(x - bf16f(hi));
  kwb[e] = hi;
  kwb[PLANE + e] = lo;
}

// single-buffer B load for k-tile S
#define LOADB(S) do {                                                        \
  _Pragma("unroll")                                                          \
  for (int ks = 0; ks < 4; ++ks) {                                           \
    const unsigned short* bp = kwb + ((((S) * 2 + ub) * 4 + ks) * 512) + l*8;\
    bh[ks] = *(const bf16x8v*)(bp);                                          \
    bl[ks] = *(const bf16x8v*)(bp + PLANE);                                  \
  } } while (0)

#define MFMA12(ACC) do {                                                     \
  _Pragma("unroll")                                                          \
  for (int ks = 0; ks < 4; ++ks) {                                           \
    ACC = __builtin_amdgcn_mfma_f32_32x32x16_bf16(ah[ks], bh[ks], ACC, 0,0,0); \
    ACC = __builtin_amdgcn_mfma_f32_32x32x16_bf16(al[ks], bh[ks], ACC, 0,0,0); \
    ACC = __builtin_amdgcn_mfma_f32_32x32x16_bf16(ah[ks], bl[ks], ACC, 0,0,0); \
  } } while (0)

#define ZERO(ACC) do { _Pragma("unroll")                                     \
  for (int zi = 0; zi < 16; ++zi) ACC[zi] = 0.f; } while (0)

__global__ __launch_bounds__(256)
void lrsig_chunk_kernel(const float* __restrict__ X,
                        const unsigned short* __restrict__ kwb,
                        float* __restrict__ wmaps)
{
  // 32768 B total:
  //   bytes [0,8192)      : dXa bf16 hi plane, swizzled [64 rows][128 B]
  //   bytes [8192,16384)  : lo plane
  //   floats [4096,8191]  : raw fp32 X tile during staging; after MFMA reused
  //                         as map slots [2 rt][NQ][NU]
  __shared__ __align__(16) float smemf[8192];
  char* smem = (char*)smemf;
  float* rawf = smemf + 4096;

  const int b   = blockIdx.y;
  const int c   = blockIdx.x;        // 0..31, 64 rows per WG
  const int tid = threadIdx.x;
  const int l   = tid & 63;
  const int w   = tid >> 6;          // wave 0..3
  const int rt  = w >> 1;            // row-tile (rows rt*32 .. +31)
  const int ub  = w & 1;             // u-block  (u = ub*32 + col)
  const int col = l & 31;
  const int hi8 = l >> 5;
  const int t0  = c * 64;

  // ---- 1. batch-issue the 16 staging loads (rows t0-1 .. t0+63, 65x63) ----
  float sv[16];
  {
    const float* Xb = X + (size_t)b * TT * NFX;
    const int base = (t0 - 1) * NFX;
#pragma unroll
    for (int ii = 0; ii < 16; ++ii) {
      int i = tid + ii * 256;
      int off = base + i + ((c == 0 && i < NFX) ? NFX : 0); // c==0: dup row 0
      sv[ii] = (i < 65 * NFX) ? Xb[off] : 0.f;
    }
  }

  // ---- 2. issue nt0's B-frags (32 VGPR); they land under staging ----
  bf16x8v bh[4], bl[4];
  LOADB(0);

  // ---- 3. store staged tile to LDS ----
#pragma unroll
  for (int ii = 0; ii < 16; ++ii) {
    int i = tid + ii * 256;
    if (i < 65 * NFX) rawf[i] = sv[ii];
  }
  __syncthreads();

  // ---- 4. diff + bf16 hi/lo split into swizzled planes ----
  {
    float v0[16], v1[16];
#pragma unroll
    for (int ii = 0; ii < 16; ++ii) {
      int e = tid + ii * 256;
      if (e < 64 * NFX) { v0[ii] = rawf[e]; v1[ii] = rawf[e + NFX]; }
    }
#pragma unroll
    for (int ii = 0; ii < 16; ++ii) {
      int e = tid + ii * 256;
      if (e < 64 * NFX) {
        int r2 = e / NFX;
        int c2 = e - r2 * NFX;             // feature-1 (features 1..63)
        float d = v1[ii] - v0[ii];         // row-0 dup makes t=0 diff zero
        unsigned short h  = bf16_rne(d);
        unsigned short lo = bf16_rne(d - bf16f(h));
        int byte = r2 * 128 + ((2 * (c2 + 1)) ^ ((r2 & 7) << 4));
        *(unsigned short*)(smem + byte)        = h;
        *(unsigned short*)(smem + 8192 + byte) = lo;
      }
    }
  }
  if (tid < 64) {                      // time feature f=0
    int r2 = tid;
    float d = (t0 + r2 == 0) ? 0.f : (2.0f / 2047.0f);
    unsigned short h  = bf16_rne(d);
    unsigned short lo = bf16_rne(d - bf16f(h));
    int byte = r2 * 128 + ((0) ^ ((r2 & 7) << 4));
    *(unsigned short*)(smem + byte)        = h;
    *(unsigned short*)(smem + 8192 + byte) = lo;
  }
  __syncthreads();

  const int row = rt * 32 + col;
  const int colbase = ub * 32 + col;

  // ---- A-frags once for all phases (same row) ----
  bf16x8v ah[4], al[4];
#pragma unroll
  for (int ks = 0; ks < 4; ++ks) {
    const int f0 = ks * 16 + hi8 * 8;
    const int abyte = row * 128 + ((2 * f0) ^ ((row & 7) << 4));
    ah[ks] = *(const bf16x8v*)(smem + abyte);
    al[ks] = *(const bf16x8v*)(smem + 8192 + abyte);
  }

  float Ao[4], Aa1[4], Ad1[4];
  float Ba3[4], BaA[4], Bd3[4], BdA[4], BtA3[4];

  // ---- phase A: nt 0,1,2 ----
  {
    f32x16v accA[3];
    ZERO(accA[0]); ZERO(accA[1]); ZERO(accA[2]);
    MFMA12(accA[0]); LOADB(1);
    MFMA12(accA[1]); LOADB(2);
    MFMA12(accA[2]); LOADB(3);
    // scan chain A per 4-row run (covers nt3 load latency)
#pragma unroll
    for (int j = 0; j < 4; ++j) {
      float o = 0.f, a1 = 0.f, lc1 = 0.f;
#pragma unroll
      for (int i = 0; i < 4; ++i) {
        const int r = 4 * j + i;
        float m0 = accA[0][r], m1 = accA[1][r], m2 = accA[2][r];
        o   += m0 + m2 * (lc1 + 0.5f * m1);
        a1  += m2;
        lc1 += m1;
      }
      Ao[j] = o; Aa1[j] = a1; Ad1[j] = lc1;
    }
  }

  // ---- phase B: nt 3,4,5 ----
  {
    f32x16v accB[3];
    ZERO(accB[0]); ZERO(accB[1]); ZERO(accB[2]);
    MFMA12(accB[0]); LOADB(4);
    MFMA12(accB[1]); LOADB(5);
    MFMA12(accB[2]); LOADB(6);
    // scan chain B per run (covers nt6 load latency)
#pragma unroll
    for (int j = 0; j < 4; ++j) {
      float o = 0.f, a3 = 0.f, aA = 0.f, lc3 = 0.f, lcA = 0.f, g4 = 0.f;
#pragma unroll
      for (int i = 0; i < 4; ++i) {
        const int r = 4 * j + i;
        float m3 = accB[0][r], m4 = accB[1][r], m5 = accB[2][r];
        float s0 = m4 * lc3;
        float s1 = 0.5f * m4 * m3;
        o   += m5 * (lcA + 0.5f * s0 + (1.f/3.f) * s1);
        a3  += m5 * (g4 + 0.5f * m4);
        aA  += m5;
        lcA += s0 + s1;
        g4  += m4;
        lc3 += m3;
      }
      Ao[j] += o;
      Ba3[j] = a3; BaA[j] = aA; Bd3[j] = lc3; BdA[j] = lcA; BtA3[j] = g4;
    }
  }

  // ---- phase C: nt 6,7,8,9 + serial scan/compose tail (minimal liveness) ----
  float tot[NQ];
  {
    f32x16v accC[4];
    ZERO(accC[0]); ZERO(accC[1]); ZERO(accC[2]); ZERO(accC[3]);
    MFMA12(accC[0]); LOADB(7);
    MFMA12(accC[1]); LOADB(8);
    MFMA12(accC[2]); LOADB(9);
    MFMA12(accC[3]);

    // per run j: scan -> mj -> shfl -> compose -> fold into tot
#pragma unroll
    for (int j = 0; j < 4; ++j) {
      float o = 0.f, a6 = 0.f, aP = 0.f, aQ = 0.f;
      float lc6 = 0.f, lcP = 0.f, lcQ = 0.f, g7 = 0.f, g8 = 0.f, hh = 0.f;
#pragma unroll
      for (int i = 0; i < 4; ++i) {
        const int r = 4 * j + i;
        float m6 = accC[0][r], m7 = accC[1][r], m8 = accC[2][r], m9 = accC[3][r];
        float p0 = m7 * lc6;
        float p1 = 0.5f * m7 * m6;
        float q0 = m8 * lcP;
        float q1 = 0.5f * m8 * p0;
        float q2 = (1.f/3.f) * m8 * p1;
        o   += m9 * (lcQ + 0.5f * q0 + (1.f/3.f) * q1 + 0.25f * q2);
        a6  += m9 * (hh + m8 * (0.5f * g7 + (1.f/6.f) * m7));
        aP  += m9 * (g8 + 0.5f * m8);
        aQ  += m9;
        hh  += m8 * (g7 + 0.5f * m7);   // exclusive g7, before update
        lcP += p0 + p1;
        lcQ += q0 + q1 + q2;
        g7 += m7; g8 += m8; lc6 += m6;
      }
      float mj[NQ];
      mj[Qo] = Ao[j] + o;
      mj[Qa1] = Aa1[j]; mj[Qa3] = Ba3[j]; mj[QaA] = BaA[j];
      mj[Qa6] = a6;     mj[QaP] = aP;     mj[QaQ] = aQ;
      mj[Qd1] = Ad1[j]; mj[Qd3] = Bd3[j]; mj[QdA] = BdA[j];
      mj[Qd6] = lc6;    mj[QdP] = lcP;    mj[QdQ] = lcQ;
      mj[QtA3] = BtA3[j]; mj[QtP6] = g7;  mj[QtQP] = g8; mj[QtQ6] = hh;

      // exchange with partner lane (g even <-> g odd), compose 8-row map
      float q1v[NQ], q2v[NQ], m8r[NQ];
#pragma unroll
      for (int q = 0; q < NQ; ++q) {
        float oth = __shfl_xor(mj[q], 32);
        q1v[q] = hi8 ? oth : mj[q];       // even g = earlier rows
        q2v[q] = hi8 ? mj[q] : oth;
      }
      compose_maps(q1v, q2v, m8r);

      if (j == 0) {
#pragma unroll
        for (int q = 0; q < NQ; ++q) tot[q] = m8r[q];
      } else {
        float nt_[NQ];
        compose_maps(tot, m8r, nt_);
#pragma unroll
        for (int q = 0; q < NQ; ++q) tot[q] = nt_[q];
      }
    }
  }

  // ---- write the two 32-row maps (one per rt) into LDS (raw area is dead) --
  if (hi8 == 0) {
    float* p = &rawf[(rt * NQ) * NU + colbase];
#pragma unroll
    for (int q = 0; q < NQ; ++q) p[q * NU] = tot[q];
  }
  __syncthreads();

  // ---- final compose rt0 o rt1 -> 64-row WG map -> ws ----
  if (tid < NU) {
    const int uu = tid;
    float q1v[NQ], q2v[NQ], rv[NQ];
#pragma unroll
    for (int q = 0; q < NQ; ++q) {
      q1v[q] = rawf[(0 * NQ + q) * NU + uu];
      q2v[q] = rawf[(1 * NQ + q) * NU + uu];
    }
    compose_maps(q1v, q2v, rv);
    float* p = &wmaps[(((size_t)b * NCC + c) * NQ) * NU + uu];
#pragma unroll
    for (int q = 0; q < NQ; ++q) p[q * NU] = rv[q];
  }
}

// ---- combine: partial 8-map folds (4 segs x 64 u) + LDS handoff + final ----
__global__ __launch_bounds__(256)
void lrsig_combine_kernel(const float* __restrict__ wmaps,
                          float* __restrict__ out)
{
  __shared__ float sm[NSEG * NQ * NU];   // 17408 B
  const int b   = blockIdx.x;            // 32 blocks
  const int seg = threadIdx.x >> 6;      // 0..3
  const int u   = threadIdx.x & 63;

  float tot[NQ];
  {
    const float* p0 = &wmaps[(((size_t)b * NCC + seg * 8) * NQ) * NU + u];
#pragma unroll
    for (int q = 0; q < NQ; ++q) tot[q] = p0[q * NU];
  }
  for (int i = 1; i < 8; ++i) {
    const float* p = &wmaps[(((size_t)b * NCC + seg * 8 + i) * NQ) * NU + u];
    float m[NQ], r[NQ];
#pragma unroll
    for (int q = 0; q < NQ; ++q) m[q] = p[q * NU];
    compose_maps(tot, m, r);
#pragma unroll
    for (int q = 0; q < NQ; ++q) tot[q] = r[q];
  }
#pragma unroll
  for (int q = 0; q < NQ; ++q) sm[(seg * NQ + q) * NU + u] = tot[q];
  __syncthreads();

  if (threadIdx.x < NU) {
    const int uu = threadIdx.x;
    float c1 = 0.f, c3 = 0.f, cA = 0.f, c6 = 0.f, cP = 0.f, cQ = 0.f, o = 0.f;
#pragma unroll
    for (int s = 0; s < NSEG; ++s) {
      float q[NQ];
#pragma unroll
      for (int i = 0; i < NQ; ++i) q[i] = sm[(s * NQ + i) * NU + uu];
      o  += q[0] + q[1]*c1 + q[2]*c3 + q[3]*cA + q[4]*c6 + q[5]*cP + q[6]*cQ;
      cA += q[13]*c3 + q[9];             // uses c3_in
      cQ += q[15]*cP + q[16]*c6 + q[12]; // uses cP_in, c6_in
      cP += q[14]*c6 + q[11];            // uses c6_in
      c1 += q[7]; c3 += q[8]; c6 += q[10];
    }
    out[b * 64 + uu] = o;
  }
}

extern "C" void kernel_launch(void* const* d_in, const int* in_sizes, int n_in,
                              void* d_out, int out_size, void* d_ws, size_t ws_size,
                              hipStream_t stream) {
  const float* X  = (const float*)d_in[0];   // (32, 2048, 63) fp32
  const float* Kw = (const float*)d_in[1];   // (64, 10, 64)   fp32
  float* out = (float*)d_out;                // (32, 64)       fp32
  float* wmaps = (float*)d_ws;                                    // 4.45 MB
  unsigned short* kwb = (unsigned short*)((char*)d_ws + MAPS_BYTES); // 160 KB

  hipLaunchKernelGGL(lrsig_prep_kernel, dim3(160), dim3(256), 0, stream,
                     Kw, kwb);
  hipLaunchKernelGGL(lrsig_chunk_kernel, dim3(NCC, 32), dim3(256), 0, stream,
                     X, kwb, wmaps);
  hipLaunchKernelGGL(lrsig_combine_kernel, dim3(32), dim3(256), 0, stream,
                     wmaps, out);
}

// Round 14
// 42.101 us; speedup vs baseline: 1.1544x; 1.1502x over previous
//
#include <hip/hip_runtime.h>

// LowRankSig_HigherOrder: B=32, T=2048, F=64 (time + 63), K=10 tensors, U=64 units.
// Round 14: chain-specialized waves. r11-r13 all sat at 1 wave/SIMD because the
// 10-tile accumulator (160 AGPR) + ~136 arch VGPR > 256 regs/wave, and the
// allocator does not overlap scoped acc arrays. Fix: the 17-param affine map
// FACTORS BY CHAIN (verified on the compose formulas): params
//   AB = {o,a1,a3,aA,d1,d3,dA,tA3}  and  C = {o,a6,aP,aQ,d6,dP,dQ,tP6,tQP,tQ6}
// compose independently (o adds). So each WG runs 8 waves (512 thr):
// wave = (rt, ub, cg); cg0 = n-tiles 0..5 + chains A/B (96 AGPR),
// cg1 = n-tiles 6..9 + chain C (64 AGPR). Peak ~200 regs -> 2 waves/SIMD.
// Maps stored as 18 slots (o_AB, AB params | o_C, C params); combine folds 18.
// C/D layout (HW-verified m74/m101): col=lane&31, row=(reg&3)+8*(reg>>2)+4*hi8.
// All scan/compose math validated rounds 1-13 (subset composes are literal
// sub-formulas of the validated full compose).

#define TT 2048
#define NFX 63
#define KT 10
#define NU 64
#define NQS 18       // map slots: [0..7]=AB, [8..17]=C
#define NCC 32       // 64-row chunks per batch
#define NSEG 4       // combine segments (8 maps each)

#define MAPS_BYTES (32u * NCC * NQS * NU * 4u)         // 4,718,592 B
#define PLANE      40960u                              // elems per bf16 plane

typedef __attribute__((ext_vector_type(16))) float f32x16v;
typedef __attribute__((ext_vector_type(8)))  short bf16x8v;

// AB slots (local idx): 0 o, 1 a1, 2 a3, 3 aA, 4 d1, 5 d3, 6 dA, 7 tA3
// C  slots (local idx): 0 o, 1 a6, 2 aP, 3 aQ, 4 d6, 5 dP, 6 dQ, 7 tP6, 8 tQP, 9 tQ6

__device__ __forceinline__ unsigned short bf16_rne(float x) {
  unsigned int u = __float_as_uint(x);
  unsigned int r = (u + 0x7FFFu + ((u >> 16) & 1u)) >> 16;
  return (unsigned short)r;
}
__device__ __forceinline__ float bf16f(unsigned short h) {
  return __uint_as_float(((unsigned int)h) << 16);
}

// chain A+B partial compose (subset of validated full compose)
__device__ __forceinline__ void compose_ab(const float* q1, const float* q2,
                                           float* r)
{
  r[0] = q1[0] + q2[0] + q2[1]*q1[4] + q2[2]*q1[5] + q2[3]*q1[6];
  r[1] = q1[1] + q2[1];
  r[2] = q1[2] + q2[2] + q1[7]*q2[3];
  r[3] = q1[3] + q2[3];
  r[4] = q1[4] + q2[4];
  r[5] = q1[5] + q2[5];
  r[6] = q1[6] + q2[6] + q2[7]*q1[5];
  r[7] = q1[7] + q2[7];
}

// chain C partial compose (subset of validated full compose)
__device__ __forceinline__ void compose_c(const float* q1, const float* q2,
                                          float* r)
{
  r[0] = q1[0] + q2[0] + q2[1]*q1[4] + q2[2]*q1[5] + q2[3]*q1[6];
  r[1] = q1[1] + q2[1] + q1[7]*q2[2] + q1[9]*q2[3];
  r[2] = q1[2] + q2[2] + q1[8]*q2[3];
  r[3] = q1[3] + q2[3];
  r[4] = q1[4] + q2[4];
  r[5] = q1[5] + q2[5] + q2[7]*q1[4];
  r[6] = q1[6] + q2[6] + q2[8]*q1[5] + q2[9]*q1[4];
  r[7] = q1[7] + q2[7];
  r[8] = q1[8] + q2[8];
  r[9] = q1[9] + q2[9] + q2[8]*q1[7];
}

// ---- prep: split Kw into bf16 hi/lo planes, FRAG-MAJOR layout:
//      idx = (((nt*2 + ub)*4 + ks)*64 + lane)*8 + j
//      lane=(hi8*32+col): f = ks*16 + hi8*8 + j, u = ub*32 + col, k = nt.
__global__ __launch_bounds__(256)
void lrsig_prep_kernel(const float* __restrict__ Kw,
                       unsigned short* __restrict__ kwb)
{
  int e = blockIdx.x * 256 + threadIdx.x;    // 0..40959 (destination index)
  int j  = e & 7;
  int l  = (e >> 3) & 63;
  int ks = (e >> 9) & 3;
  int ub = (e >> 11) & 1;
  int nt = e >> 12;
  int f = ks * 16 + (l >> 5) * 8 + j;
  int u = ub * 32 + (l & 31);
  float x = Kw[(f * KT + nt) * NU + u];
  unsigned short hi = bf16_rne(x);
  unsigned short lo = bf16_rne(x - bf16f(hi));
  kwb[e] = hi;
  kwb[PLANE + e] = lo;
}

#define LOADB(S) do {                                                        \
  _Pragma("unroll")                                                          \
  for (int ks = 0; ks < 4; ++ks) {                                           \
    const unsigned short* bp = kwb + ((((S) * 2 + ub) * 4 + ks) * 512) + l*8;\
    bh[ks] = *(const bf16x8v*)(bp);                                          \
    bl[ks] = *(const bf16x8v*)(bp + PLANE);                                  \
  } } while (0)

#define MFMA12(ACC) do {                                                     \
  _Pragma("unroll")                                                          \
  for (int ks = 0; ks < 4; ++ks) {                                           \
    ACC = __builtin_amdgcn_mfma_f32_32x32x16_bf16(ah[ks], bh[ks], ACC, 0,0,0); \
    ACC = __builtin_amdgcn_mfma_f32_32x32x16_bf16(al[ks], bh[ks], ACC, 0,0,0); \
    ACC = __builtin_amdgcn_mfma_f32_32x32x16_bf16(ah[ks], bl[ks], ACC, 0,0,0); \
  } } while (0)

#define ZERO(ACC) do { _Pragma("unroll")                                     \
  for (int zi = 0; zi < 16; ++zi) ACC[zi] = 0.f; } while (0)

__global__ __launch_bounds__(512)
void lrsig_chunk_kernel(const float* __restrict__ X,
                        const unsigned short* __restrict__ kwb,
                        float* __restrict__ wmaps)
{
  // 32768 B total:
  //   bytes [0,8192)      : dXa bf16 hi plane, swizzled [64 rows][128 B]
  //   bytes [8192,16384)  : lo plane
  //   floats [4096,8191]  : raw fp32 X tile during staging; after MFMA reused
  //                         as partial-map slots [2 rt][NQS][NU] (2304 floats)
  __shared__ __align__(16) float smemf[8192];
  char* smem = (char*)smemf;
  float* rawf = smemf + 4096;

  const int b   = blockIdx.y;
  const int c   = blockIdx.x;        // 0..31, 64 rows per WG
  const int tid = threadIdx.x;       // 0..511
  const int l   = tid & 63;
  const int w   = tid >> 6;          // wave 0..7
  const int cg  = w & 1;             // chain group: 0 = A+B (nt 0..5), 1 = C (nt 6..9)
  const int ub  = (w >> 1) & 1;      // u-block  (u = ub*32 + col)
  const int rt  = w >> 2;            // row-tile (rows rt*32 .. +31)
  const int col = l & 31;
  const int hi8 = l >> 5;
  const int t0  = c * 64;

  // ---- 1. batch-issue the 8 staging loads (rows t0-1 .. t0+63, 65x63) ----
  float sv[8];
  {
    const float* Xb = X + (size_t)b * TT * NFX;
    const int base = (t0 - 1) * NFX;
#pragma unroll
    for (int ii = 0; ii < 8; ++ii) {
      int i = tid + ii * 512;
      int off = base + i + ((c == 0 && i < NFX) ? NFX : 0); // c==0: dup row 0
      sv[ii] = (i < 65 * NFX) ? Xb[off] : 0.f;
    }
  }

  // ---- 2. issue this wave's first B-frags; they land under staging ----
  bf16x8v bh[4], bl[4];
  LOADB(cg ? 6 : 0);

  // ---- 3. store staged tile to LDS ----
#pragma unroll
  for (int ii = 0; ii < 8; ++ii) {
    int i = tid + ii * 512;
    if (i < 65 * NFX) rawf[i] = sv[ii];
  }
  __syncthreads();

  // ---- 4. diff + bf16 hi/lo split into swizzled planes ----
  {
    float v0[8], v1[8];
#pragma unroll
    for (int ii = 0; ii < 8; ++ii) {
      int e = tid + ii * 512;
      if (e < 64 * NFX) { v0[ii] = rawf[e]; v1[ii] = rawf[e + NFX]; }
    }
#pragma unroll
    for (int ii = 0; ii < 8; ++ii) {
      int e = tid + ii * 512;
      if (e < 64 * NFX) {
        int r2 = e / NFX;
        int c2 = e - r2 * NFX;             // feature-1 (features 1..63)
        float d = v1[ii] - v0[ii];         // row-0 dup makes t=0 diff zero
        unsigned short h  = bf16_rne(d);
        unsigned short lo = bf16_rne(d - bf16f(h));
        int byte = r2 * 128 + ((2 * (c2 + 1)) ^ ((r2 & 7) << 4));
        *(unsigned short*)(smem + byte)        = h;
        *(unsigned short*)(smem + 8192 + byte) = lo;
      }
    }
  }
  if (tid < 64) {                      // time feature f=0
    int r2 = tid;
    float d = (t0 + r2 == 0) ? 0.f : (2.0f / 2047.0f);
    unsigned short h  = bf16_rne(d);
    unsigned short lo = bf16_rne(d - bf16f(h));
    int byte = r2 * 128 + ((0) ^ ((r2 & 7) << 4));
    *(unsigned short*)(smem + byte)        = h;
    *(unsigned short*)(smem + 8192 + byte) = lo;
  }
  __syncthreads();

  const int row = rt * 32 + col;
  const int colbase = ub * 32 + col;

  // ---- A-frags (same for all tiles of this wave) ----
  bf16x8v ah[4], al[4];
#pragma unroll
  for (int ks = 0; ks < 4; ++ks) {
    const int f0 = ks * 16 + hi8 * 8;
    const int abyte = row * 128 + ((2 * f0) ^ ((row & 7) << 4));
    ah[ks] = *(const bf16x8v*)(smem + abyte);
    al[ks] = *(const bf16x8v*)(smem + 8192 + abyte);
  }

  if (cg == 0) {
    // ================= chain group A+B: n-tiles 0..5 =================
    f32x16v acc[6];
    ZERO(acc[0]); ZERO(acc[1]); ZERO(acc[2]);
    ZERO(acc[3]); ZERO(acc[4]); ZERO(acc[5]);
    MFMA12(acc[0]); LOADB(1);
    MFMA12(acc[1]); LOADB(2);
    MFMA12(acc[2]); LOADB(3);
    MFMA12(acc[3]); LOADB(4);
    MFMA12(acc[4]); LOADB(5);
    MFMA12(acc[5]);

    float tot[8];
#pragma unroll
    for (int j = 0; j < 4; ++j) {
      float oA = 0.f, a1 = 0.f, lc1 = 0.f;
      float oB = 0.f, a3 = 0.f, aA = 0.f, lc3 = 0.f, lcA = 0.f, g4 = 0.f;
#pragma unroll
      for (int i = 0; i < 4; ++i) {
        const int r = 4 * j + i;
        float m0 = acc[0][r], m1 = acc[1][r], m2 = acc[2][r];
        float m3 = acc[3][r], m4 = acc[4][r], m5 = acc[5][r];
        // chain A
        oA  += m0 + m2 * (lc1 + 0.5f * m1);
        a1  += m2;
        lc1 += m1;
        // chain B
        float s0 = m4 * lc3;
        float s1 = 0.5f * m4 * m3;
        oB  += m5 * (lcA + 0.5f * s0 + (1.f/3.f) * s1);
        a3  += m5 * (g4 + 0.5f * m4);
        aA  += m5;
        lcA += s0 + s1;
        g4  += m4;
        lc3 += m3;
      }
      float pm[8] = {oA + oB, a1, a3, aA, lc1, lc3, lcA, g4};
      // exchange with partner lane (g even <-> g odd), compose 8-row map
      float q1v[8], q2v[8], m8r[8];
#pragma unroll
      for (int q = 0; q < 8; ++q) {
        float oth = __shfl_xor(pm[q], 32);
        q1v[q] = hi8 ? oth : pm[q];       // even g = earlier rows
        q2v[q] = hi8 ? pm[q] : oth;
      }
      compose_ab(q1v, q2v, m8r);
      if (j == 0) {
#pragma unroll
        for (int q = 0; q < 8; ++q) tot[q] = m8r[q];
      } else {
        float nx[8];
        compose_ab(tot, m8r, nx);
#pragma unroll
        for (int q = 0; q < 8; ++q) tot[q] = nx[q];
      }
    }
    if (hi8 == 0) {
      float* p = &rawf[(rt * NQS) * NU + colbase];
#pragma unroll
      for (int q = 0; q < 8; ++q) p[q * NU] = tot[q];
    }
  } else {
    // ================= chain group C: n-tiles 6..9 =================
    f32x16v acc[4];
    ZERO(acc[0]); ZERO(acc[1]); ZERO(acc[2]); ZERO(acc[3]);
    MFMA12(acc[0]); LOADB(7);
    MFMA12(acc[1]); LOADB(8);
    MFMA12(acc[2]); LOADB(9);
    MFMA12(acc[3]);

    float tot[10];
#pragma unroll
    for (int j = 0; j < 4; ++j) {
      float o = 0.f, a6 = 0.f, aP = 0.f, aQ = 0.f;
      float lc6 = 0.f, lcP = 0.f, lcQ = 0.f, g7 = 0.f, g8 = 0.f, hh = 0.f;
#pragma unroll
      for (int i = 0; i < 4; ++i) {
        const int r = 4 * j + i;
        float m6 = acc[0][r], m7 = acc[1][r], m8 = acc[2][r], m9 = acc[3][r];
        float p0 = m7 * lc6;
        float p1 = 0.5f * m7 * m6;
        float q0 = m8 * lcP;
        float q1 = 0.5f * m8 * p0;
        float q2 = (1.f/3.f) * m8 * p1;
        o   += m9 * (lcQ + 0.5f * q0 + (1.f/3.f) * q1 + 0.25f * q2);
        a6  += m9 * (hh + m8 * (0.5f * g7 + (1.f/6.f) * m7));
        aP  += m9 * (g8 + 0.5f * m8);
        aQ  += m9;
        hh  += m8 * (g7 + 0.5f * m7);   // exclusive g7, before update
        lcP += p0 + p1;
        lcQ += q0 + q1 + q2;
        g7 += m7; g8 += m8; lc6 += m6;
      }
      float pm[10] = {o, a6, aP, aQ, lc6, lcP, lcQ, g7, g8, hh};
      float q1v[10], q2v[10], m8r[10];
#pragma unroll
      for (int q = 0; q < 10; ++q) {
        float oth = __shfl_xor(pm[q], 32);
        q1v[q] = hi8 ? oth : pm[q];
        q2v[q] = hi8 ? pm[q] : oth;
      }
      compose_c(q1v, q2v, m8r);
      if (j == 0) {
#pragma unroll
        for (int q = 0; q < 10; ++q) tot[q] = m8r[q];
      } else {
        float nx[10];
        compose_c(tot, m8r, nx);
#pragma unroll
        for (int q = 0; q < 10; ++q) tot[q] = nx[q];
      }
    }
    if (hi8 == 0) {
      float* p = &rawf[(rt * NQS + 8) * NU + colbase];
#pragma unroll
      for (int q = 0; q < 10; ++q) p[q * NU] = tot[q];
    }
  }
  __syncthreads();

  // ---- final compose rt0 o rt1 (AB and C independently) -> ws ----
  if (tid < NU) {                      // AB params, slots 0..7
    const int uu = tid;
    float q1v[8], q2v[8], rv[8];
#pragma unroll
    for (int q = 0; q < 8; ++q) {
      q1v[q] = rawf[(0 * NQS + q) * NU + uu];
      q2v[q] = rawf[(1 * NQS + q) * NU + uu];
    }
    compose_ab(q1v, q2v, rv);
    float* p = &wmaps[(((size_t)b * NCC + c) * NQS) * NU + uu];
#pragma unroll
    for (int q = 0; q < 8; ++q) p[q * NU] = rv[q];
  } else if (tid < 2 * NU) {           // C params, slots 8..17
    const int uu = tid - NU;
    float q1v[10], q2v[10], rv[10];
#pragma unroll
    for (int q = 0; q < 10; ++q) {
      q1v[q] = rawf[(0 * NQS + 8 + q) * NU + uu];
      q2v[q] = rawf[(1 * NQS + 8 + q) * NU + uu];
    }
    compose_c(q1v, q2v, rv);
    float* p = &wmaps[(((size_t)b * NCC + c) * NQS + 8) * NU + uu];
#pragma unroll
    for (int q = 0; q < 10; ++q) p[q * NU] = rv[q];
  }
}

// ---- combine: partial 8-map folds (4 segs x 64 u) + LDS handoff + final ----
__global__ __launch_bounds__(256)
void lrsig_combine_kernel(const float* __restrict__ wmaps,
                          float* __restrict__ out)
{
  __shared__ float sm[NSEG * NQS * NU];  // 18432 B
  const int b   = blockIdx.x;            // 32 blocks
  const int seg = threadIdx.x >> 6;      // 0..3
  const int u   = threadIdx.x & 63;

  float tab[8], tc[10];
  {
    const float* p0 = &wmaps[(((size_t)b * NCC + seg * 8) * NQS) * NU + u];
#pragma unroll
    for (int q = 0; q < 8; ++q)  tab[q] = p0[q * NU];
#pragma unroll
    for (int q = 0; q < 10; ++q) tc[q]  = p0[(8 + q) * NU];
  }
  for (int i = 1; i < 8; ++i) {
    const float* p = &wmaps[(((size_t)b * NCC + seg * 8 + i) * NQS) * NU + u];
    float mab[8], mc[10], rab[8], rc[10];
#pragma unroll
    for (int q = 0; q < 8; ++q)  mab[q] = p[q * NU];
#pragma unroll
    for (int q = 0; q < 10; ++q) mc[q]  = p[(8 + q) * NU];
    compose_ab(tab, mab, rab);
    compose_c(tc, mc, rc);
#pragma unroll
    for (int q = 0; q < 8; ++q)  tab[q] = rab[q];
#pragma unroll
    for (int q = 0; q < 10; ++q) tc[q]  = rc[q];
  }
#pragma unroll
  for (int q = 0; q < 8; ++q)  sm[(seg * NQS + q) * NU + u]     = tab[q];
#pragma unroll
  for (int q = 0; q < 10; ++q) sm[(seg * NQS + 8 + q) * NU + u] = tc[q];
  __syncthreads();

  if (threadIdx.x < NU) {
    const int uu = threadIdx.x;
    float c1 = 0.f, c3 = 0.f, cA = 0.f, c6 = 0.f, cP = 0.f, cQ = 0.f, o = 0.f;
#pragma unroll
    for (int s = 0; s < NSEG; ++s) {
      float q[NQS];
#pragma unroll
      for (int i = 0; i < NQS; ++i) q[i] = sm[(s * NQS + i) * NU + uu];
      // slots: 0 oAB,1 a1,2 a3,3 aA,4 d1,5 d3,6 dA,7 tA3,
      //        8 oC,9 a6,10 aP,11 aQ,12 d6,13 dP,14 dQ,15 tP6,16 tQP,17 tQ6
      o  += q[0] + q[8] + q[1]*c1 + q[2]*c3 + q[3]*cA
          + q[9]*c6 + q[10]*cP + q[11]*cQ;
      cA += q[7]*c3 + q[6];              // uses c3_in
      cQ += q[16]*cP + q[17]*c6 + q[14]; // uses cP_in, c6_in
      cP += q[15]*c6 + q[13];            // uses c6_in
      c1 += q[4]; c3 += q[5]; c6 += q[12];
    }
    out[b * 64 + uu] = o;
  }
}

extern "C" void kernel_launch(void* const* d_in, const int* in_sizes, int n_in,
                              void* d_out, int out_size, void* d_ws, size_t ws_size,
                              hipStream_t stream) {
  const float* X  = (const float*)d_in[0];   // (32, 2048, 63) fp32
  const float* Kw = (const float*)d_in[1];   // (64, 10, 64)   fp32
  float* out = (float*)d_out;                // (32, 64)       fp32
  float* wmaps = (float*)d_ws;                                    // 4.72 MB
  unsigned short* kwb = (unsigned short*)((char*)d_ws + MAPS_BYTES); // 160 KB

  hipLaunchKernelGGL(lrsig_prep_kernel, dim3(160), dim3(256), 0, stream,
                     Kw, kwb);
  hipLaunchKernelGGL(lrsig_chunk_kernel, dim3(NCC, 32), dim3(512), 0, stream,
                     X, kwb, wmaps);
  hipLaunchKernelGGL(lrsig_combine_kernel, dim3(32), dim3(256), 0, stream,
                     wmaps, out);
}